// Round 9
// baseline (293.733 us; speedup 1.0000x reference)
//
#include <hip/hip_runtime.h>

#define BATCH 4096
#define NAG   8
#define OBS   64
#define HD    64
#define GH    128
#define NACT  16
#define TAU   0.025f
#define CAP   16384

typedef short  bf16x8 __attribute__((ext_vector_type(8)));
typedef unsigned short u16x8 __attribute__((ext_vector_type(8)));
typedef float  f32x4  __attribute__((ext_vector_type(4)));

// ============================================================ helpers
__device__ __forceinline__ float fast_sigmoid(float x) {
    return 1.f / (1.f + __expf(-x));
}
__device__ __forceinline__ float sigmoid_negarg(float x) {  // = 1 - sigmoid(x)
    return 1.f / (1.f + __expf(x));
}
__device__ __forceinline__ float fast_tanh(float x) {
    x = fminf(fmaxf(x, -15.f), 15.f);
    const float e = __expf(2.f * x);
    return (e - 1.f) / (e + 1.f);
}
__device__ __forceinline__ unsigned short f2bf(float f) {   // RNE f32->bf16
    unsigned int u = __builtin_bit_cast(unsigned int, f);
    u = (u + 0x7FFFu + ((u >> 16) & 1u)) >> 16;
    return (unsigned short)u;
}

// ============================================================ counter zero
__global__ void zero_counter(int* c) { if (threadIdx.x == 0) c[0] = 0; }

// ============================================================ epilogue-constant prep
// econst[5][64][128]: 0:bi+bh(r) 1:bi+bh(z) 2:bi(n) 3:bh(n) 4:dwg
__global__ __launch_bounds__(128) void bprep_kernel(
    const float* __restrict__ bi, const float* __restrict__ bh,
    const float* __restrict__ Wg, float* __restrict__ econst)
{
    const int pp = blockIdx.x;            // 0..55
    const int pi = pp / 7;
    int pj = pp % 7; pj += (pj >= pi);
    const int pb = pi * NAG + pj;
    const int c  = threadIdx.x;           // 0..127
    econst[0*8192 + pb*128 + c] = bi[pb*384 + c]       + bh[pb*384 + c];
    econst[1*8192 + pb*128 + c] = bi[pb*384 + 128 + c] + bh[pb*384 + 128 + c];
    econst[2*8192 + pb*128 + c] = bi[pb*384 + 256 + c];
    econst[3*8192 + pb*128 + c] = bh[pb*384 + 256 + c];
    econst[4*8192 + pb*128 + c] = Wg[pb*256 + 128 + c] - Wg[pb*256 + c];
}

// ============================================================ Wi -> bf16, gate-permuted
// out gate index g' = cg*48 + s*16 + cl  <- src gate g = s*128 + cg*16 + cl.
__global__ __launch_bounds__(256) void wiconv_kernel(
    const float* __restrict__ Wi, unsigned short* __restrict__ wib)
{
    const int t   = blockIdx.x * 256 + threadIdx.x;   // 0..344063
    const int pp  = t / 6144;                         // 56 off-diag pairs
    const int rem = t - pp * 6144;
    const int gp  = rem >> 4;                         // 0..383
    const int k8  = rem & 15;                         // 8-elem chunk along k
    const int pi  = pp / 7;
    int pj = pp % 7; pj += (pj >= pi);
    const int pb  = pi * NAG + pj;
    const int cg  = gp / 48;
    const int r2  = gp - cg * 48;
    const int s   = r2 >> 4, cl = r2 & 15;
    const int g   = s * GH + cg * 16 + cl;
    const float* src = Wi + ((size_t)pb * 384 + g) * GH + k8 * 8;
    u16x8 o;
#pragma unroll
    for (int e = 0; e < 8; ++e) o[e] = f2bf(src[e]);
    *reinterpret_cast<u16x8*>(wib + ((size_t)pb * 384 + gp) * GH + k8 * 8) = o;
}

// ============================================================ A: encode (+ bf16 mirror)
__global__ __launch_bounds__(256, 2) void encode_kernel(
    const float* __restrict__ obs, const float* __restrict__ W1,
    const float* __restrict__ b1, const float* __restrict__ W2,
    const float* __restrict__ b2, float* __restrict__ h,
    unsigned short* __restrict__ hb)
{
    const int n    = blockIdx.x >> 6;
    const int tile = blockIdx.x & 63;
    const int b0   = tile * 64;
    const int tid  = threadIdx.x;

    __shared__ float u1[OBS * 68];
    __shared__ float h1t[GH * 68];
    __shared__ float wl[16 * GH];

    const float* __restrict__ W1n = W1 + n * (OBS * GH);
    const float* __restrict__ W2n = W2 + n * (GH * HD);
    const float* __restrict__ b1n = b1 + n * GH;
    const float* __restrict__ b2n = b2 + n * HD;

    {
        const int c  = tid & 63;
        const int r0 = tid >> 6;
        for (int rr = 0; rr < 16; ++rr) {
            const int bb = r0 * 16 + rr;
            u1[c * 68 + bb] = obs[((size_t)(b0 + bb) * NAG + n) * OBS + c];
        }
    }

    const int bq = tid & 15;
    const int cg = tid >> 4;

    float acc1[8][4];
#pragma unroll
    for (int cc = 0; cc < 8; ++cc)
#pragma unroll
        for (int bb = 0; bb < 4; ++bb) acc1[cc][bb] = 0.f;

    for (int kc = 0; kc < 4; ++kc) {
        __syncthreads();
#pragma unroll
        for (int p = 0; p < 2; ++p) {
            const int f = tid + p * 256;
            const int k = f >> 5, c4 = f & 31;
            *reinterpret_cast<float4*>(&wl[k * GH + c4 * 4]) =
                *reinterpret_cast<const float4*>(&W1n[(kc * 16 + k) * GH + c4 * 4]);
        }
        __syncthreads();
#pragma unroll 2
        for (int k = 0; k < 16; ++k) {
            const float4 uu = *reinterpret_cast<const float4*>(
                &u1[(kc * 16 + k) * 68 + bq * 4]);
            const float ub[4] = {uu.x, uu.y, uu.z, uu.w};
            const float4 wa = *reinterpret_cast<const float4*>(&wl[k * GH + cg * 8]);
            const float4 wb = *reinterpret_cast<const float4*>(&wl[k * GH + cg * 8 + 4]);
            const float wv[8] = {wa.x, wa.y, wa.z, wa.w, wb.x, wb.y, wb.z, wb.w};
#pragma unroll
            for (int cc = 0; cc < 8; ++cc)
#pragma unroll
                for (int bb = 0; bb < 4; ++bb)
                    acc1[cc][bb] += wv[cc] * ub[bb];
        }
    }

    {
        const float4 ba  = *reinterpret_cast<const float4*>(&b1n[cg * 8]);
        const float4 bb4 = *reinterpret_cast<const float4*>(&b1n[cg * 8 + 4]);
        const float bv[8] = {ba.x, ba.y, ba.z, ba.w, bb4.x, bb4.y, bb4.z, bb4.w};
#pragma unroll
        for (int cc = 0; cc < 8; ++cc)
#pragma unroll
            for (int bb = 0; bb < 4; ++bb)
                h1t[(cg * 8 + cc) * 68 + bq * 4 + bb] =
                    fmaxf(acc1[cc][bb] + bv[cc], 0.f);
    }

    const int og = tid >> 4;
    float acc2[4][4];
#pragma unroll
    for (int oc = 0; oc < 4; ++oc)
#pragma unroll
        for (int bb = 0; bb < 4; ++bb) acc2[oc][bb] = 0.f;

    for (int kc = 0; kc < 8; ++kc) {
        __syncthreads();
        {
            const int k = tid >> 4, o4 = tid & 15;
            *reinterpret_cast<float4*>(&wl[k * HD + o4 * 4]) =
                *reinterpret_cast<const float4*>(&W2n[(kc * 16 + k) * HD + o4 * 4]);
        }
        __syncthreads();
#pragma unroll 2
        for (int k = 0; k < 16; ++k) {
            const float4 uu = *reinterpret_cast<const float4*>(
                &h1t[(kc * 16 + k) * 68 + bq * 4]);
            const float ub[4] = {uu.x, uu.y, uu.z, uu.w};
            const float4 wa = *reinterpret_cast<const float4*>(&wl[k * HD + og * 4]);
            const float wv[4] = {wa.x, wa.y, wa.z, wa.w};
#pragma unroll
            for (int oc = 0; oc < 4; ++oc)
#pragma unroll
                for (int bb = 0; bb < 4; ++bb)
                    acc2[oc][bb] += wv[oc] * ub[bb];
        }
    }

    {
        const float4 b2v = *reinterpret_cast<const float4*>(&b2n[og * 4]);
#pragma unroll
        for (int bb = 0; bb < 4; ++bb) {
            float4 o;
            o.x = fmaxf(acc2[0][bb] + b2v.x, 0.f);
            o.y = fmaxf(acc2[1][bb] + b2v.y, 0.f);
            o.z = fmaxf(acc2[2][bb] + b2v.z, 0.f);
            o.w = fmaxf(acc2[3][bb] + b2v.w, 0.f);
            const size_t row = (size_t)(b0 + bq * 4 + bb) * NAG + n;
            *reinterpret_cast<float4*>(&h[row * HD + og * 4]) = o;
            ushort4 hv;
            hv.x = f2bf(o.x); hv.y = f2bf(o.y); hv.z = f2bf(o.z); hv.w = f2bf(o.w);
            *reinterpret_cast<ushort4*>(&hb[row * HD + og * 4]) = hv;
        }
    }
}

// ============================================================ B: pairwise GRU via MFMA (v2)
// 512 thr / 8 waves: wave (h=wv>>2, g=wv&3) owns batch-half h x gate-group g.
// acc shrinks [4][6]->[2][6]: 48 AGPR + ~105 VGPR ~= 153 unified regs/wave ->
// 3 waves/SIMD (v1: 96+96=192 -> 2 waves/SIMD, Occupancy 19%, 50% stall).
// Explicit double-buffered A/B loads; MFMA issue order per acc element is
// IDENTICAL to v1 -> margins bitwise unchanged. Epilogue: precomputed econst,
// (1-z)=sigmoid(-x), conflict-free column-major part + parallel 8x8 reduce
// (v1: wave0-only 64-read serial reduce with 8-way bank conflicts).
__global__ __launch_bounds__(512, 3) void pair_mfma_kernel(
    const unsigned short* __restrict__ hb, const unsigned short* __restrict__ wib,
    const float* __restrict__ econst, const float* __restrict__ bg,
    const float* __restrict__ gum, float* __restrict__ wout,
    int* __restrict__ list, int* __restrict__ counter)
{
    const int pairp = blockIdx.x >> 6;
    const int tile  = blockIdx.x & 63;
    const int pi = pairp / 7;
    int pj = pairp % 7; pj += (pj >= pi);
    const int pb = pi * NAG + pj;
    const int b0 = tile * 64;

    const int tid = threadIdx.x;
    const int wv  = tid >> 6;          // wave 0..7
    const int g   = wv & 3;            // gate group (96 gates)
    const int hh  = wv >> 2;           // batch half (32 rows)
    const int l   = tid & 63;
    const int cl  = l & 15;
    const int rg  = l >> 4;

    f32x4 acc[2][6];
#pragma unroll
    for (int bb = 0; bb < 2; ++bb)
#pragma unroll
        for (int t = 0; t < 6; ++t) acc[bb][t] = (f32x4){0.f, 0.f, 0.f, 0.f};

    const size_t wbase = ((size_t)pb * 384 + g * 96 + cl) * GH + rg * 8;

#define LOADA(dst, kb_) { \
    const int ag = ((kb_) < 2) ? pi : pj; \
    const int ch = ((kb_) & 1) * 32 + rg * 8; \
    _Pragma("unroll") \
    for (int bb = 0; bb < 2; ++bb) { \
        const int b = b0 + (2 * hh + bb) * 16 + cl; \
        dst[bb] = *reinterpret_cast<const bf16x8*>( \
            &hb[((size_t)b * NAG + ag) * HD + ch]); } }

#define LOADB(dst, kb_) { \
    _Pragma("unroll") \
    for (int t = 0; t < 6; ++t) \
        dst[t] = *reinterpret_cast<const bf16x8*>( \
            &wib[wbase + (size_t)(kb_) * 32 + (size_t)t * 16 * GH]); }

#define MFMA6(a_, b_) { \
    _Pragma("unroll") \
    for (int t = 0; t < 6; ++t) \
    _Pragma("unroll") \
    for (int bb = 0; bb < 2; ++bb) \
        acc[bb][t] = __builtin_amdgcn_mfma_f32_16x16x32_bf16( \
            a_[bb], b_[t], acc[bb][t], 0, 0, 0); }

    bf16x8 av0[2], av1[2], bv0[6], bv1[6];
    LOADA(av0, 0); LOADB(bv0, 0);
    LOADA(av1, 1); LOADB(bv1, 1);
    MFMA6(av0, bv0);                       // kb=0
    LOADA(av0, 2); LOADB(bv0, 2);
    MFMA6(av1, bv1);                       // kb=1
    LOADA(av1, 3); LOADB(bv1, 3);
    MFMA6(av0, bv0);                       // kb=2
    MFMA6(av1, bv1);                       // kb=3
#undef LOADA
#undef LOADB
#undef MFMA6

    // ---- GRU epilogue: channel c = (2g+cgl)*16 + cl ----
    __shared__ float part[64][69];         // [col=g*16+cl][row=batch], pad 69
    __shared__ float part2[64][9];
    float pl[2][4];
#pragma unroll
    for (int bb = 0; bb < 2; ++bb)
#pragma unroll
        for (int r = 0; r < 4; ++r) pl[bb][r] = 0.f;

#pragma unroll
    for (int cgl = 0; cgl < 2; ++cgl) {
        const int c  = (2 * g + cgl) * 16 + cl;
        const float br  = econst[0 * 8192 + pb * 128 + c];
        const float bz  = econst[1 * 8192 + pb * 128 + c];
        const float bn  = econst[2 * 8192 + pb * 128 + c];
        const float bhn = econst[3 * 8192 + pb * 128 + c];
        const float dw  = econst[4 * 8192 + pb * 128 + c];
#pragma unroll
        for (int bb = 0; bb < 2; ++bb)
#pragma unroll
            for (int r = 0; r < 4; ++r) {
                const float rr  = fast_sigmoid(acc[bb][cgl * 3 + 0][r] + br);
                const float omz = sigmoid_negarg(acc[bb][cgl * 3 + 1][r] + bz);
                const float nn  = fast_tanh(acc[bb][cgl * 3 + 2][r] + bn + rr * bhn);
                pl[bb][r] += omz * nn * dw;
            }
    }
#pragma unroll
    for (int bb = 0; bb < 2; ++bb)
#pragma unroll
        for (int r = 0; r < 4; ++r)
            part[g * 16 + cl][(2 * hh + bb) * 16 + rg * 4 + r] = pl[bb][r];
    __syncthreads();

    // ---- parallel segmented reduce: 512 thr, 8 cols each ----
    {
        const int row = tid & 63, seg = tid >> 6;
        float s = 0.f;
#pragma unroll
        for (int t = 0; t < 8; ++t) s += part[seg * 8 + t][row];
        part2[row][seg] = s;
    }
    __syncthreads();

    if (tid < 64) {
        float s = 0.f;
#pragma unroll
        for (int t = 0; t < 8; ++t) s += part2[tid][t];
        const int b = b0 + tid;
        const float dbg = bg[pb * 2 + 1] - bg[pb * 2 + 0];
        const float* gp2 = gum + ((size_t)(b * NAG + pi) * NAG + pj) * 2;
        const float margin = s + dbg + (gp2[1] - gp2[0]);
        wout[(b * NAG + pi) * NAG + pj] = (margin > 0.f) ? 1.f : 0.f;
        if (fabsf(margin) < TAU) {
            const int idx = atomicAdd(counter, 1);
            if (idx < CAP) list[idx] = (b << 6) | (pi << 3) | pj;
        }
    }
}

// ============================================================ B2: exact-f32 refinement (v3)
// One BLOCK per entry (grid-stride); lane-private partials, coalesced loads,
// one shuffle-reduce per entry. Validated R8 (left top-5). tau 0.05->0.025
// halves the boundary count (bf16 margin-error sigma ~2-4e-3 -> >=6 sigma).
__global__ __launch_bounds__(256) void refine_kernel(
    const float* __restrict__ h, const float* __restrict__ Wi,
    const float* __restrict__ bi, const float* __restrict__ bh,
    const float* __restrict__ Wg, const float* __restrict__ bg,
    const float* __restrict__ gum, const int* __restrict__ list,
    const int* __restrict__ counter, float* __restrict__ wout)
{
    __shared__ float u_sh[128];         // u = [h_i ; h_j]
    __shared__ float part[384 * 9];     // per-gate partials, padded stride 9
    __shared__ float pl_sh[128];        // per-channel logit contributions

    const int tid = threadIdx.x;
    const int rs  = tid >> 3;           // row slot 0..31
    const int fs  = tid & 7;            // float4 slot 0..7
    int count = counter[0]; if (count > CAP) count = CAP;

    for (int e = blockIdx.x; e < count; e += gridDim.x) {
        const int code = list[e];
        const int b = code >> 6, pi2 = (code >> 3) & 7, pj2 = code & 7;
        const int pb = pi2 * NAG + pj2;
        const float* __restrict__ Wr = Wi + (size_t)pb * 384 * GH;

        if (tid < 32) {
            const float* src = (tid < 16)
                ? h + ((size_t)b * NAG + pi2) * HD + tid * 4
                : h + ((size_t)b * NAG + pj2) * HD + (tid - 16) * 4;
            *reinterpret_cast<float4*>(&u_sh[tid * 4]) =
                *reinterpret_cast<const float4*>(src);
        }
        __syncthreads();

        float4 uv[4];
#pragma unroll
        for (int s = 0; s < 4; ++s)
            uv[s] = *reinterpret_cast<const float4*>(&u_sh[(fs + 8 * s) * 4]);

#pragma unroll 2
        for (int si = 0; si < 12; ++si) {
            const int r = si * 32 + rs;
            const float* row = Wr + (size_t)r * GH;
            float p = 0.f;
#pragma unroll
            for (int s = 0; s < 4; ++s) {
                const float4 wv = *reinterpret_cast<const float4*>(
                    row + (fs + 8 * s) * 4);
                p += wv.x * uv[s].x + wv.y * uv[s].y
                   + wv.z * uv[s].z + wv.w * uv[s].w;
            }
            part[r * 9 + fs] = p;
        }
        __syncthreads();

        // ---- per-channel GRU: thread c in [0,128) ----
        if (tid < 128) {
            const int c = tid;
            float gr = 0.f, gz = 0.f, gn = 0.f;
#pragma unroll
            for (int k = 0; k < 8; ++k) {
                gr += part[c * 9 + k];
                gz += part[(128 + c) * 9 + k];
                gn += part[(256 + c) * 9 + k];
            }
            const float r = fast_sigmoid(gr + bi[pb*384 + c] + bh[pb*384 + c]);
            const float z = fast_sigmoid(gz + bi[pb*384 + 128 + c] + bh[pb*384 + 128 + c]);
            const float n = fast_tanh(gn + bi[pb*384 + 256 + c]
                                      + r * bh[pb*384 + 256 + c]);
            pl_sh[c] = (1.f - z) * n * (Wg[pb*256 + 128 + c] - Wg[pb*256 + c]);
        }
        __syncthreads();

        if (tid < 64) {
            float p = pl_sh[tid] + pl_sh[tid + 64];
#pragma unroll
            for (int m = 1; m < 64; m <<= 1) p += __shfl_xor(p, m, 64);
            if (tid == 0) {
                const float dbg = bg[pb * 2 + 1] - bg[pb * 2 + 0];
                const float* gp2 = gum + ((size_t)(b * NAG + pi2) * NAG + pj2) * 2;
                const float margin = p + dbg + (gp2[1] - gp2[0]);
                wout[(b * NAG + pi2) * NAG + pj2] = (margin > 0.f) ? 1.f : 0.f;
            }
        }
        __syncthreads();   // all reads done before next entry's stores
    }
}

// ============================================================ C: aggregate + decode
__global__ __launch_bounds__(256, 2) void agg_kernel(
    const float* __restrict__ h, const float* __restrict__ w,
    const float* __restrict__ Wd, const float* __restrict__ bd,
    float* __restrict__ q)
{
    const int b0 = blockIdx.x * 8;
    __shared__ float hl[8 * 520];
    const int tid = threadIdx.x;
#pragma unroll
    for (int p = 0; p < 4; ++p) {
        const int f = tid + p * 256;
        const int r = f >> 7, cc = (f & 127) * 4;
        *reinterpret_cast<float4*>(&hl[r * 520 + cc]) =
            *reinterpret_cast<const float4*>(&h[(size_t)b0 * 512 + f * 4]);
    }
    __syncthreads();

    const int aq = tid & 3;
    const int i  = (tid >> 2) & 7;
    const int bb = tid >> 5;
    const int b  = b0 + bb;

    float other[HD];
#pragma unroll
    for (int c = 0; c < HD; ++c) other[c] = 0.f;
    const float* wrow = w + ((size_t)b * NAG + i) * NAG;
    for (int j = 0; j < NAG; ++j) {
        if (j == i) continue;
        const float wv = wrow[j];
        const float* hr = &hl[bb * 520 + j * 64];
#pragma unroll
        for (int c4 = 0; c4 < HD / 4; ++c4) {
            const float4 v = *reinterpret_cast<const float4*>(hr + c4 * 4);
            other[c4*4+0] += wv * v.x; other[c4*4+1] += wv * v.y;
            other[c4*4+2] += wv * v.z; other[c4*4+3] += wv * v.w;
        }
    }
    const float* hi = &hl[bb * 520 + i * 64];
    const float* __restrict__ Wdp = Wd + (i * NACT) * (2 * HD);
    float qo[4];
#pragma unroll
    for (int t = 0; t < 4; ++t) {
        const int a = aq * 4 + t;
        float acc0 = bd[i * NACT + a];
        const float* wr = Wdp + a * 2 * HD;
#pragma unroll
        for (int c4 = 0; c4 < HD / 4; ++c4) {
            const float4 w1 = *reinterpret_cast<const float4*>(wr + c4 * 4);
            const float4 w2 = *reinterpret_cast<const float4*>(wr + 64 + c4 * 4);
            acc0 += hi[c4*4+0] * w1.x + hi[c4*4+1] * w1.y
                  + hi[c4*4+2] * w1.z + hi[c4*4+3] * w1.w
                  + other[c4*4+0] * w2.x + other[c4*4+1] * w2.y
                  + other[c4*4+2] * w2.z + other[c4*4+3] * w2.w;
        }
        qo[t] = acc0;
    }
    float4 qv = {qo[0], qo[1], qo[2], qo[3]};
    *reinterpret_cast<float4*>(&q[((size_t)b * NAG + i) * NACT + aq * 4]) = qv;
}

// ============================================================ launch
// ws layout (float units) — stays within the proven ~20.2MB footprint:
//   h @ 0 (8MB) | w @ 2,097,152 (1MB) | hb @ 2,359,296 (4MB)
//   wib @ 3,407,872 (6MB) | list @ 4,980,736 (16K ints, CAP shrunk)
//   cnt @ 4,997,120 | econst @ 4,997,184 (5*64*128 = 40,960 f32)
extern "C" void kernel_launch(void* const* d_in, const int* in_sizes, int n_in,
                              void* d_out, int out_size, void* d_ws, size_t ws_size,
                              hipStream_t stream) {
    const float* obs = (const float*)d_in[0];
    const float* gum = (const float*)d_in[1];
    const float* W1  = (const float*)d_in[2];
    const float* b1  = (const float*)d_in[3];
    const float* W2  = (const float*)d_in[4];
    const float* b2  = (const float*)d_in[5];
    const float* Wi  = (const float*)d_in[6];
    const float* bi  = (const float*)d_in[7];
    const float* bh  = (const float*)d_in[8];
    const float* Wg  = (const float*)d_in[9];
    const float* bg  = (const float*)d_in[10];
    const float* Wd  = (const float*)d_in[11];
    const float* bd  = (const float*)d_in[12];
    float* q = (float*)d_out;

    float*          ws     = (float*)d_ws;
    float*          h      = ws;
    float*          w      = ws + 2097152;
    unsigned short* hb     = (unsigned short*)(ws + 2359296);
    unsigned short* wib    = (unsigned short*)(ws + 3407872);
    int*            list   = (int*)(ws + 4980736);
    int*            cnt    = (int*)(ws + 4997120);
    float*          econst = ws + 4997184;

    hipLaunchKernelGGL(zero_counter, dim3(1), dim3(64), 0, stream, cnt);
    hipLaunchKernelGGL(bprep_kernel, dim3(56), dim3(128), 0, stream,
                       bi, bh, Wg, econst);
    hipLaunchKernelGGL(wiconv_kernel, dim3(1344), dim3(256), 0, stream, Wi, wib);
    hipLaunchKernelGGL(encode_kernel, dim3(NAG * (BATCH / 64)), dim3(256), 0, stream,
                       obs, W1, b1, W2, b2, h, hb);
    hipLaunchKernelGGL(pair_mfma_kernel, dim3(56 * 64), dim3(512), 0, stream,
                       hb, wib, econst, bg, gum, w, list, cnt);
    hipLaunchKernelGGL(refine_kernel, dim3(2048), dim3(256), 0, stream,
                       h, Wi, bi, bh, Wg, bg, gum, list, cnt, w);
    hipLaunchKernelGGL(agg_kernel, dim3(BATCH / 8), dim3(256), 0, stream,
                       h, w, Wd, bd, q);
}

// Round 10
// 268.465 us; speedup vs baseline: 1.0941x; 1.0941x over previous
//
#include <hip/hip_runtime.h>

#define BATCH 4096
#define NAG   8
#define OBS   64
#define HD    64
#define GH    128
#define NACT  16
#define TAU   0.025f
#define CAP   16384

typedef short  bf16x8 __attribute__((ext_vector_type(8)));
typedef unsigned short u16x8 __attribute__((ext_vector_type(8)));
typedef float  f32x4  __attribute__((ext_vector_type(4)));

// ============================================================ helpers
// exact-path helpers (refine only — validated R8 behavior, unchanged)
__device__ __forceinline__ float fast_sigmoid(float x) {
    return 1.f / (1.f + __expf(-x));
}
__device__ __forceinline__ float fast_tanh(float x) {
    x = fminf(fmaxf(x, -15.f), 15.f);
    const float e = __expf(2.f * x);
    return (e - 1.f) / (e + 1.f);
}
// division-free fast path (pair epilogue; ~1ulp via v_rcp — error 1e-6 << TAU)
__device__ __forceinline__ float fsig(float x) {        // sigmoid
    return __builtin_amdgcn_rcpf(1.f + __expf(-x));
}
__device__ __forceinline__ float fsig_neg(float x) {    // 1 - sigmoid(x)
    return __builtin_amdgcn_rcpf(1.f + __expf(x));
}
__device__ __forceinline__ float ftanh(float x) {       // limits ok at +-inf
    return 1.f - 2.f * __builtin_amdgcn_rcpf(1.f + __expf(2.f * x));
}
__device__ __forceinline__ unsigned short f2bf(float f) {   // RNE f32->bf16
    unsigned int u = __builtin_bit_cast(unsigned int, f);
    u = (u + 0x7FFFu + ((u >> 16) & 1u)) >> 16;
    return (unsigned short)u;
}

// ============================================================ counter zero
__global__ void zero_counter(int* c) { if (threadIdx.x == 0) c[0] = 0; }

// ============================================================ epilogue-constant prep
// econst[5][64][128]: 0:bi+bh(r) 1:bi+bh(z) 2:bi(n) 3:bh(n) 4:dwg
__global__ __launch_bounds__(128) void bprep_kernel(
    const float* __restrict__ bi, const float* __restrict__ bh,
    const float* __restrict__ Wg, float* __restrict__ econst)
{
    const int pp = blockIdx.x;            // 0..55
    const int pi = pp / 7;
    int pj = pp % 7; pj += (pj >= pi);
    const int pb = pi * NAG + pj;
    const int c  = threadIdx.x;           // 0..127
    econst[0*8192 + pb*128 + c] = bi[pb*384 + c]       + bh[pb*384 + c];
    econst[1*8192 + pb*128 + c] = bi[pb*384 + 128 + c] + bh[pb*384 + 128 + c];
    econst[2*8192 + pb*128 + c] = bi[pb*384 + 256 + c];
    econst[3*8192 + pb*128 + c] = bh[pb*384 + 256 + c];
    econst[4*8192 + pb*128 + c] = Wg[pb*256 + 128 + c] - Wg[pb*256 + c];
}

// ============================================================ Wi -> bf16, gate-permuted
// out gate index g' = cg*48 + s*16 + cl  <- src gate g = s*128 + cg*16 + cl.
__global__ __launch_bounds__(256) void wiconv_kernel(
    const float* __restrict__ Wi, unsigned short* __restrict__ wib)
{
    const int t   = blockIdx.x * 256 + threadIdx.x;   // 0..344063
    const int pp  = t / 6144;                         // 56 off-diag pairs
    const int rem = t - pp * 6144;
    const int gp  = rem >> 4;                         // 0..383
    const int k8  = rem & 15;                         // 8-elem chunk along k
    const int pi  = pp / 7;
    int pj = pp % 7; pj += (pj >= pi);
    const int pb  = pi * NAG + pj;
    const int cg  = gp / 48;
    const int r2  = gp - cg * 48;
    const int s   = r2 >> 4, cl = r2 & 15;
    const int g   = s * GH + cg * 16 + cl;
    const float* src = Wi + ((size_t)pb * 384 + g) * GH + k8 * 8;
    u16x8 o;
#pragma unroll
    for (int e = 0; e < 8; ++e) o[e] = f2bf(src[e]);
    *reinterpret_cast<u16x8*>(wib + ((size_t)pb * 384 + gp) * GH + k8 * 8) = o;
}

// ============================================================ A: encode (+ bf16 mirror)
__global__ __launch_bounds__(256, 2) void encode_kernel(
    const float* __restrict__ obs, const float* __restrict__ W1,
    const float* __restrict__ b1, const float* __restrict__ W2,
    const float* __restrict__ b2, float* __restrict__ h,
    unsigned short* __restrict__ hb)
{
    const int n    = blockIdx.x >> 6;
    const int tile = blockIdx.x & 63;
    const int b0   = tile * 64;
    const int tid  = threadIdx.x;

    __shared__ float u1[OBS * 68];
    __shared__ float h1t[GH * 68];
    __shared__ float wl[16 * GH];

    const float* __restrict__ W1n = W1 + n * (OBS * GH);
    const float* __restrict__ W2n = W2 + n * (GH * HD);
    const float* __restrict__ b1n = b1 + n * GH;
    const float* __restrict__ b2n = b2 + n * HD;

    {
        const int c  = tid & 63;
        const int r0 = tid >> 6;
        for (int rr = 0; rr < 16; ++rr) {
            const int bb = r0 * 16 + rr;
            u1[c * 68 + bb] = obs[((size_t)(b0 + bb) * NAG + n) * OBS + c];
        }
    }

    const int bq = tid & 15;
    const int cg = tid >> 4;

    float acc1[8][4];
#pragma unroll
    for (int cc = 0; cc < 8; ++cc)
#pragma unroll
        for (int bb = 0; bb < 4; ++bb) acc1[cc][bb] = 0.f;

    for (int kc = 0; kc < 4; ++kc) {
        __syncthreads();
#pragma unroll
        for (int p = 0; p < 2; ++p) {
            const int f = tid + p * 256;
            const int k = f >> 5, c4 = f & 31;
            *reinterpret_cast<float4*>(&wl[k * GH + c4 * 4]) =
                *reinterpret_cast<const float4*>(&W1n[(kc * 16 + k) * GH + c4 * 4]);
        }
        __syncthreads();
#pragma unroll 2
        for (int k = 0; k < 16; ++k) {
            const float4 uu = *reinterpret_cast<const float4*>(
                &u1[(kc * 16 + k) * 68 + bq * 4]);
            const float ub[4] = {uu.x, uu.y, uu.z, uu.w};
            const float4 wa = *reinterpret_cast<const float4*>(&wl[k * GH + cg * 8]);
            const float4 wb = *reinterpret_cast<const float4*>(&wl[k * GH + cg * 8 + 4]);
            const float wv[8] = {wa.x, wa.y, wa.z, wa.w, wb.x, wb.y, wb.z, wb.w};
#pragma unroll
            for (int cc = 0; cc < 8; ++cc)
#pragma unroll
                for (int bb = 0; bb < 4; ++bb)
                    acc1[cc][bb] += wv[cc] * ub[bb];
        }
    }

    {
        const float4 ba  = *reinterpret_cast<const float4*>(&b1n[cg * 8]);
        const float4 bb4 = *reinterpret_cast<const float4*>(&b1n[cg * 8 + 4]);
        const float bv[8] = {ba.x, ba.y, ba.z, ba.w, bb4.x, bb4.y, bb4.z, bb4.w};
#pragma unroll
        for (int cc = 0; cc < 8; ++cc)
#pragma unroll
            for (int bb = 0; bb < 4; ++bb)
                h1t[(cg * 8 + cc) * 68 + bq * 4 + bb] =
                    fmaxf(acc1[cc][bb] + bv[cc], 0.f);
    }

    const int og = tid >> 4;
    float acc2[4][4];
#pragma unroll
    for (int oc = 0; oc < 4; ++oc)
#pragma unroll
        for (int bb = 0; bb < 4; ++bb) acc2[oc][bb] = 0.f;

    for (int kc = 0; kc < 8; ++kc) {
        __syncthreads();
        {
            const int k = tid >> 4, o4 = tid & 15;
            *reinterpret_cast<float4*>(&wl[k * HD + o4 * 4]) =
                *reinterpret_cast<const float4*>(&W2n[(kc * 16 + k) * HD + o4 * 4]);
        }
        __syncthreads();
#pragma unroll 2
        for (int k = 0; k < 16; ++k) {
            const float4 uu = *reinterpret_cast<const float4*>(
                &h1t[(kc * 16 + k) * 68 + bq * 4]);
            const float ub[4] = {uu.x, uu.y, uu.z, uu.w};
            const float4 wa = *reinterpret_cast<const float4*>(&wl[k * HD + og * 4]);
            const float wv[4] = {wa.x, wa.y, wa.z, wa.w};
#pragma unroll
            for (int oc = 0; oc < 4; ++oc)
#pragma unroll
                for (int bb = 0; bb < 4; ++bb)
                    acc2[oc][bb] += wv[oc] * ub[bb];
        }
    }

    {
        const float4 b2v = *reinterpret_cast<const float4*>(&b2n[og * 4]);
#pragma unroll
        for (int bb = 0; bb < 4; ++bb) {
            float4 o;
            o.x = fmaxf(acc2[0][bb] + b2v.x, 0.f);
            o.y = fmaxf(acc2[1][bb] + b2v.y, 0.f);
            o.z = fmaxf(acc2[2][bb] + b2v.z, 0.f);
            o.w = fmaxf(acc2[3][bb] + b2v.w, 0.f);
            const size_t row = (size_t)(b0 + bq * 4 + bb) * NAG + n;
            *reinterpret_cast<float4*>(&h[row * HD + og * 4]) = o;
            ushort4 hv;
            hv.x = f2bf(o.x); hv.y = f2bf(o.y); hv.z = f2bf(o.z); hv.w = f2bf(o.w);
            *reinterpret_cast<ushort4*>(&hb[row * HD + og * 4]) = hv;
        }
    }
}

// ============================================================ B: pairwise GRU via MFMA (v3)
// 512 thr / 8 waves. Wave wv owns gates [wv*48, wv*48+48) = channel-group wv
// x ALL 64 batch rows: acc[4][3] = 48 AGPR. Each B-fragment is read by
// exactly ONE wave (v2: two -> per-block B-traffic 192KB; v3: 96KB). The
// redundancy moves to A (hb, 4MB, L2-hot everywhere -> cheap). Per-acc
// MFMA chain still kb=0,1,2,3 -> margins bitwise unchanged vs R8/R9.
// Epilogue: division-free activations (v_rcp), conflict-light [128][69]
// partials. R9 lesson: occupancy was NOT the limiter; B-traffic + div-heavy
// VALU (47us measured) were.
__global__ __launch_bounds__(512, 2) void pair_mfma_kernel(
    const unsigned short* __restrict__ hb, const unsigned short* __restrict__ wib,
    const float* __restrict__ econst, const float* __restrict__ bg,
    const float* __restrict__ gum, float* __restrict__ wout,
    int* __restrict__ list, int* __restrict__ counter)
{
    const int pairp = blockIdx.x >> 6;
    const int tile  = blockIdx.x & 63;
    const int pi = pairp / 7;
    int pj = pairp % 7; pj += (pj >= pi);
    const int pb = pi * NAG + pj;
    const int b0 = tile * 64;

    const int tid = threadIdx.x;
    const int wv  = tid >> 6;          // wave 0..7 = channel group
    const int l   = tid & 63;
    const int cl  = l & 15;
    const int rg  = l >> 4;

    f32x4 acc[4][3];                   // [batch-tile][s in r/z/n]
#pragma unroll
    for (int bt = 0; bt < 4; ++bt)
#pragma unroll
        for (int t = 0; t < 3; ++t) acc[bt][t] = (f32x4){0.f, 0.f, 0.f, 0.f};

    const size_t wbase = ((size_t)pb * 384 + wv * 48 + cl) * GH + rg * 8;

#define LOADA(dst, kb_) { \
    const int ag = ((kb_) < 2) ? pi : pj; \
    const int ch = ((kb_) & 1) * 32 + rg * 8; \
    _Pragma("unroll") \
    for (int bt = 0; bt < 4; ++bt) { \
        const int b = b0 + bt * 16 + cl; \
        dst[bt] = *reinterpret_cast<const bf16x8*>( \
            &hb[((size_t)b * NAG + ag) * HD + ch]); } }

#define LOADB(dst, kb_) { \
    _Pragma("unroll") \
    for (int t = 0; t < 3; ++t) \
        dst[t] = *reinterpret_cast<const bf16x8*>( \
            &wib[wbase + (size_t)(kb_) * 32 + (size_t)t * 16 * GH]); }

#define MFMA3(a_, b_) { \
    _Pragma("unroll") \
    for (int t = 0; t < 3; ++t) \
    _Pragma("unroll") \
    for (int bt = 0; bt < 4; ++bt) \
        acc[bt][t] = __builtin_amdgcn_mfma_f32_16x16x32_bf16( \
            a_[bt], b_[t], acc[bt][t], 0, 0, 0); }

    bf16x8 av0[4], av1[4], bv0[3], bv1[3];
    LOADA(av0, 0); LOADB(bv0, 0);
    LOADA(av1, 1); LOADB(bv1, 1);
    MFMA3(av0, bv0);                       // kb=0
    LOADA(av0, 2); LOADB(bv0, 2);
    MFMA3(av1, bv1);                       // kb=1
    LOADA(av1, 3); LOADB(bv1, 3);
    MFMA3(av0, bv0);                       // kb=2
    MFMA3(av1, bv1);                       // kb=3
#undef LOADA
#undef LOADB
#undef MFMA3

    // ---- GRU epilogue: channel c = wv*16 + cl (one per lane) ----
    __shared__ float part[128 * 69];       // [channel][batch-row], pad 69
    __shared__ float part2[64 * 9];
    {
        const int c   = wv * 16 + cl;
        const float br  = econst[0 * 8192 + pb * 128 + c];
        const float bz  = econst[1 * 8192 + pb * 128 + c];
        const float bn  = econst[2 * 8192 + pb * 128 + c];
        const float bhn = econst[3 * 8192 + pb * 128 + c];
        const float dw  = econst[4 * 8192 + pb * 128 + c];
#pragma unroll
        for (int bt = 0; bt < 4; ++bt)
#pragma unroll
            for (int r = 0; r < 4; ++r) {
                const float rr  = fsig(acc[bt][0][r] + br);
                const float omz = fsig_neg(acc[bt][1][r] + bz);
                const float nn  = ftanh(acc[bt][2][r] + bn + rr * bhn);
                part[c * 69 + bt * 16 + rg * 4 + r] = omz * nn * dw;
            }
    }
    __syncthreads();

    // ---- reduce: 512 thr sum 16 channels each, then 64 sum 8 segs ----
    {
        const int row = tid & 63, seg = tid >> 6;
        float s = 0.f;
#pragma unroll
        for (int t = 0; t < 16; ++t) s += part[(seg * 16 + t) * 69 + row];
        part2[row * 9 + seg] = s;
    }
    __syncthreads();

    if (tid < 64) {
        float s = 0.f;
#pragma unroll
        for (int t = 0; t < 8; ++t) s += part2[tid * 9 + t];
        const int b = b0 + tid;
        const float dbg = bg[pb * 2 + 1] - bg[pb * 2 + 0];
        const float* gp2 = gum + ((size_t)(b * NAG + pi) * NAG + pj) * 2;
        const float margin = s + dbg + (gp2[1] - gp2[0]);
        wout[(b * NAG + pi) * NAG + pj] = (margin > 0.f) ? 1.f : 0.f;
        if (fabsf(margin) < TAU) {
            const int idx = atomicAdd(counter, 1);
            if (idx < CAP) list[idx] = (b << 6) | (pi << 3) | pj;
        }
    }
}

// ============================================================ B2: exact-f32 refinement (v3)
// One BLOCK per entry (grid-stride); lane-private partials, coalesced loads,
// one shuffle-reduce per entry. Validated R8 (left top-5). Uses the exact
// (division-based) activations on purpose.
__global__ __launch_bounds__(256) void refine_kernel(
    const float* __restrict__ h, const float* __restrict__ Wi,
    const float* __restrict__ bi, const float* __restrict__ bh,
    const float* __restrict__ Wg, const float* __restrict__ bg,
    const float* __restrict__ gum, const int* __restrict__ list,
    const int* __restrict__ counter, float* __restrict__ wout)
{
    __shared__ float u_sh[128];         // u = [h_i ; h_j]
    __shared__ float part[384 * 9];     // per-gate partials, padded stride 9
    __shared__ float pl_sh[128];        // per-channel logit contributions

    const int tid = threadIdx.x;
    const int rs  = tid >> 3;           // row slot 0..31
    const int fs  = tid & 7;            // float4 slot 0..7
    int count = counter[0]; if (count > CAP) count = CAP;

    for (int e = blockIdx.x; e < count; e += gridDim.x) {
        const int code = list[e];
        const int b = code >> 6, pi2 = (code >> 3) & 7, pj2 = code & 7;
        const int pb = pi2 * NAG + pj2;
        const float* __restrict__ Wr = Wi + (size_t)pb * 384 * GH;

        if (tid < 32) {
            const float* src = (tid < 16)
                ? h + ((size_t)b * NAG + pi2) * HD + tid * 4
                : h + ((size_t)b * NAG + pj2) * HD + (tid - 16) * 4;
            *reinterpret_cast<float4*>(&u_sh[tid * 4]) =
                *reinterpret_cast<const float4*>(src);
        }
        __syncthreads();

        float4 uv[4];
#pragma unroll
        for (int s = 0; s < 4; ++s)
            uv[s] = *reinterpret_cast<const float4*>(&u_sh[(fs + 8 * s) * 4]);

#pragma unroll 2
        for (int si = 0; si < 12; ++si) {
            const int r = si * 32 + rs;
            const float* row = Wr + (size_t)r * GH;
            float p = 0.f;
#pragma unroll
            for (int s = 0; s < 4; ++s) {
                const float4 wv = *reinterpret_cast<const float4*>(
                    row + (fs + 8 * s) * 4);
                p += wv.x * uv[s].x + wv.y * uv[s].y
                   + wv.z * uv[s].z + wv.w * uv[s].w;
            }
            part[r * 9 + fs] = p;
        }
        __syncthreads();

        // ---- per-channel GRU: thread c in [0,128) ----
        if (tid < 128) {
            const int c = tid;
            float gr = 0.f, gz = 0.f, gn = 0.f;
#pragma unroll
            for (int k = 0; k < 8; ++k) {
                gr += part[c * 9 + k];
                gz += part[(128 + c) * 9 + k];
                gn += part[(256 + c) * 9 + k];
            }
            const float r = fast_sigmoid(gr + bi[pb*384 + c] + bh[pb*384 + c]);
            const float z = fast_sigmoid(gz + bi[pb*384 + 128 + c] + bh[pb*384 + 128 + c]);
            const float n = fast_tanh(gn + bi[pb*384 + 256 + c]
                                      + r * bh[pb*384 + 256 + c]);
            pl_sh[c] = (1.f - z) * n * (Wg[pb*256 + 128 + c] - Wg[pb*256 + c]);
        }
        __syncthreads();

        if (tid < 64) {
            float p = pl_sh[tid] + pl_sh[tid + 64];
#pragma unroll
            for (int m = 1; m < 64; m <<= 1) p += __shfl_xor(p, m, 64);
            if (tid == 0) {
                const float dbg = bg[pb * 2 + 1] - bg[pb * 2 + 0];
                const float* gp2 = gum + ((size_t)(b * NAG + pi2) * NAG + pj2) * 2;
                const float margin = p + dbg + (gp2[1] - gp2[0]);
                wout[(b * NAG + pi2) * NAG + pj2] = (margin > 0.f) ? 1.f : 0.f;
            }
        }
        __syncthreads();   // all reads done before next entry's stores
    }
}

// ============================================================ C: aggregate + decode
__global__ __launch_bounds__(256, 2) void agg_kernel(
    const float* __restrict__ h, const float* __restrict__ w,
    const float* __restrict__ Wd, const float* __restrict__ bd,
    float* __restrict__ q)
{
    const int b0 = blockIdx.x * 8;
    __shared__ float hl[8 * 520];
    const int tid = threadIdx.x;
#pragma unroll
    for (int p = 0; p < 4; ++p) {
        const int f = tid + p * 256;
        const int r = f >> 7, cc = (f & 127) * 4;
        *reinterpret_cast<float4*>(&hl[r * 520 + cc]) =
            *reinterpret_cast<const float4*>(&h[(size_t)b0 * 512 + f * 4]);
    }
    __syncthreads();

    const int aq = tid & 3;
    const int i  = (tid >> 2) & 7;
    const int bb = tid >> 5;
    const int b  = b0 + bb;

    float other[HD];
#pragma unroll
    for (int c = 0; c < HD; ++c) other[c] = 0.f;
    const float* wrow = w + ((size_t)b * NAG + i) * NAG;
    for (int j = 0; j < NAG; ++j) {
        if (j == i) continue;
        const float wv = wrow[j];
        const float* hr = &hl[bb * 520 + j * 64];
#pragma unroll
        for (int c4 = 0; c4 < HD / 4; ++c4) {
            const float4 v = *reinterpret_cast<const float4*>(hr + c4 * 4);
            other[c4*4+0] += wv * v.x; other[c4*4+1] += wv * v.y;
            other[c4*4+2] += wv * v.z; other[c4*4+3] += wv * v.w;
        }
    }
    const float* hi = &hl[bb * 520 + i * 64];
    const float* __restrict__ Wdp = Wd + (i * NACT) * (2 * HD);
    float qo[4];
#pragma unroll
    for (int t = 0; t < 4; ++t) {
        const int a = aq * 4 + t;
        float acc0 = bd[i * NACT + a];
        const float* wr = Wdp + a * 2 * HD;
#pragma unroll
        for (int c4 = 0; c4 < HD / 4; ++c4) {
            const float4 w1 = *reinterpret_cast<const float4*>(wr + c4 * 4);
            const float4 w2 = *reinterpret_cast<const float4*>(wr + 64 + c4 * 4);
            acc0 += hi[c4*4+0] * w1.x + hi[c4*4+1] * w1.y
                  + hi[c4*4+2] * w1.z + hi[c4*4+3] * w1.w
                  + other[c4*4+0] * w2.x + other[c4*4+1] * w2.y
                  + other[c4*4+2] * w2.z + other[c4*4+3] * w2.w;
        }
        qo[t] = acc0;
    }
    float4 qv = {qo[0], qo[1], qo[2], qo[3]};
    *reinterpret_cast<float4*>(&q[((size_t)b * NAG + i) * NACT + aq * 4]) = qv;
}

// ============================================================ launch
// ws layout (float units):
//   h @ 0 (8MB) | w @ 2,097,152 (1MB) | hb @ 2,359,296 (4MB)
//   wib @ 3,407,872 (6MB) | list @ 4,980,736 (16K ints)
//   cnt @ 4,997,120 | econst @ 4,997,184 (5*64*128 f32)
extern "C" void kernel_launch(void* const* d_in, const int* in_sizes, int n_in,
                              void* d_out, int out_size, void* d_ws, size_t ws_size,
                              hipStream_t stream) {
    const float* obs = (const float*)d_in[0];
    const float* gum = (const float*)d_in[1];
    const float* W1  = (const float*)d_in[2];
    const float* b1  = (const float*)d_in[3];
    const float* W2  = (const float*)d_in[4];
    const float* b2  = (const float*)d_in[5];
    const float* Wi  = (const float*)d_in[6];
    const float* bi  = (const float*)d_in[7];
    const float* bh  = (const float*)d_in[8];
    const float* Wg  = (const float*)d_in[9];
    const float* bg  = (const float*)d_in[10];
    const float* Wd  = (const float*)d_in[11];
    const float* bd  = (const float*)d_in[12];
    float* q = (float*)d_out;

    float*          ws     = (float*)d_ws;
    float*          h      = ws;
    float*          w      = ws + 2097152;
    unsigned short* hb     = (unsigned short*)(ws + 2359296);
    unsigned short* wib    = (unsigned short*)(ws + 3407872);
    int*            list   = (int*)(ws + 4980736);
    int*            cnt    = (int*)(ws + 4997120);
    float*          econst = ws + 4997184;

    hipLaunchKernelGGL(zero_counter, dim3(1), dim3(64), 0, stream, cnt);
    hipLaunchKernelGGL(bprep_kernel, dim3(56), dim3(128), 0, stream,
                       bi, bh, Wg, econst);
    hipLaunchKernelGGL(wiconv_kernel, dim3(1344), dim3(256), 0, stream, Wi, wib);
    hipLaunchKernelGGL(encode_kernel, dim3(NAG * (BATCH / 64)), dim3(256), 0, stream,
                       obs, W1, b1, W2, b2, h, hb);
    hipLaunchKernelGGL(pair_mfma_kernel, dim3(56 * 64), dim3(512), 0, stream,
                       hb, wib, econst, bg, gum, w, list, cnt);
    hipLaunchKernelGGL(refine_kernel, dim3(2048), dim3(256), 0, stream,
                       h, Wi, bi, bh, Wg, bg, gum, list, cnt, w);
    hipLaunchKernelGGL(agg_kernel, dim3(BATCH / 8), dim3(256), 0, stream,
                       h, w, Wd, bd, q);
}